// Round 2
// baseline (218.425 us; speedup 1.0000x reference)
//
#include <hip/hip_runtime.h>

// ArtNetwork: y = sigmoid(Wout @ tanh(W8 @ ... tanh(W1 @ tanh(Win@x+b)) ...))
// Design:
//  - Hidden 16x16 layers via v_mfma_f32_16x16x16_f16 with A=W, B=h^T.
//    C/D layout (row=(lane>>4)*4+i, col=lane&15) == B layout (k=(lane>>4)*4+j,
//    n=lane&15), so MFMA out -> tanh -> cvt_pkrtz -> next B frag. No LDS/shuffle.
//  - tanh(z) = 1 - 2*rcp(1+exp2(y)), y = 2*log2(e)*z with the scale folded into
//    the f16 weights, so MFMA emits y directly. 4 instrs/tanh.
//  - sigmoid(z) = rcp(1+exp2(-log2(e)*z)), scale folded into Wout.
//  - 2 tiles (32 points) per wave iteration for ILP; persistent grid,
//    weights preloaded once per wave.

typedef float  f32x4 __attribute__((ext_vector_type(4)));
typedef __fp16 f16x4 __attribute__((ext_vector_type(4)));
typedef __fp16 f16x2 __attribute__((ext_vector_type(2)));

#define K2   2.8853900817779268f    // 2*log2(e)
#define KOUT (-1.4426950408889634f) // -log2(e)

__device__ __forceinline__ float tanh_from_y(float y) {
    // y = 2*log2(e)*z  ->  tanh(z) = 1 - 2/(1+2^y)
    float e = __builtin_amdgcn_exp2f(y);
    float r = __builtin_amdgcn_rcpf(e + 1.0f);
    return __builtin_fmaf(-2.0f, r, 1.0f);
}

__device__ __forceinline__ f16x4 pack4(float a, float b, float c, float d) {
    f16x2 lo = __builtin_amdgcn_cvt_pkrtz(a, b);
    f16x2 hi = __builtin_amdgcn_cvt_pkrtz(c, d);
    return __builtin_shufflevector(lo, hi, 0, 1, 2, 3);
}

__global__ __launch_bounds__(256, 4)
void artnet_kernel(const float2* __restrict__ x,     // [N][2]
                   const float2* __restrict__ Win,   // [16][2]
                   const float*  __restrict__ bin,   // [16]
                   const float4* __restrict__ Wh,    // [8][16][16]
                   const float4* __restrict__ Wout,  // [3][16]
                   float* __restrict__ out,          // [N][3]
                   int nPairs, int nWaves)
{
    const int tid  = blockIdx.x * 256 + threadIdx.x;
    const int gw   = tid >> 6;            // global wave id
    const int lane = threadIdx.x & 63;
    const int row  = lane & 15;           // m / point-col index
    const int quad = lane >> 4;           // 0..3

    // ---- Preload hidden-layer A fragments: A[m=row][k=quad*4+j] = K2*W[l][row][k]
    f16x4 aw[8];
#pragma unroll
    for (int l = 0; l < 8; ++l) {
        float4 w = Wh[l * 64 + row * 4 + quad];
        aw[l] = pack4(w.x * K2, w.y * K2, w.z * K2, w.w * K2);
    }

    // ---- Input layer constants (features quad*4+j), pre-scaled by K2
    float wi0[4], wi1[4], bb[4];
#pragma unroll
    for (int j = 0; j < 4; ++j) {
        float2 wr = Win[quad * 4 + j];
        wi0[j] = wr.x * K2;
        wi1[j] = wr.y * K2;
        bb[j]  = bin[quad * 4 + j] * K2;
    }

    // ---- Output layer constants, pre-scaled by -log2(e)
    float wo0[4], wo1[4], wo2[4];
    {
        float4 w0 = Wout[0 * 4 + quad];
        float4 w1 = Wout[1 * 4 + quad];
        float4 w2 = Wout[2 * 4 + quad];
        wo0[0] = w0.x * KOUT; wo0[1] = w0.y * KOUT; wo0[2] = w0.z * KOUT; wo0[3] = w0.w * KOUT;
        wo1[0] = w1.x * KOUT; wo1[1] = w1.y * KOUT; wo1[2] = w1.z * KOUT; wo1[3] = w1.w * KOUT;
        wo2[0] = w2.x * KOUT; wo2[1] = w2.y * KOUT; wo2[2] = w2.z * KOUT; wo2[3] = w2.w * KOUT;
    }

    const f32x4 zero4 = {0.0f, 0.0f, 0.0f, 0.0f};

    for (int pi = gw; pi < nPairs; pi += nWaves) {
        const int t0 = pi * 2;           // first tile of the pair
        f16x4 bf[2];
        float tl[2][4];

        // ---- Input layer: h1 = tanh(x @ Win^T + b), built in B-frag layout
#pragma unroll
        for (int s = 0; s < 2; ++s) {
            float2 xv = x[(t0 + s) * 16 + row];
            float h0 = tanh_from_y(__builtin_fmaf(xv.x, wi0[0], __builtin_fmaf(xv.y, wi1[0], bb[0])));
            float h1 = tanh_from_y(__builtin_fmaf(xv.x, wi0[1], __builtin_fmaf(xv.y, wi1[1], bb[1])));
            float h2 = tanh_from_y(__builtin_fmaf(xv.x, wi0[2], __builtin_fmaf(xv.y, wi1[2], bb[2])));
            float h3 = tanh_from_y(__builtin_fmaf(xv.x, wi0[3], __builtin_fmaf(xv.y, wi1[3], bb[3])));
            bf[s] = pack4(h0, h1, h2, h3);
        }

        // ---- 8 hidden layers: MFMA -> tanh -> repack (layouts line up)
#pragma unroll
        for (int l = 0; l < 8; ++l) {
#pragma unroll
            for (int s = 0; s < 2; ++s) {
                f32x4 acc = __builtin_amdgcn_mfma_f32_16x16x16f16(aw[l], bf[s], zero4, 0, 0, 0);
                float u0 = tanh_from_y(acc[0]);
                float u1 = tanh_from_y(acc[1]);
                float u2 = tanh_from_y(acc[2]);
                float u3 = tanh_from_y(acc[3]);
                bf[s] = pack4(u0, u1, u2, u3);
                if (l == 7) { tl[s][0] = u0; tl[s][1] = u1; tl[s][2] = u2; tl[s][3] = u3; }
            }
        }

        // ---- Output layer 16->3 + sigmoid. Cross-quad reduce via shfl_xor.
#pragma unroll
        for (int s = 0; s < 2; ++s) {
            float p0 = 0.0f, p1 = 0.0f, p2 = 0.0f;
#pragma unroll
            for (int j = 0; j < 4; ++j) {
                p0 = __builtin_fmaf(tl[s][j], wo0[j], p0);
                p1 = __builtin_fmaf(tl[s][j], wo1[j], p1);
                p2 = __builtin_fmaf(tl[s][j], wo2[j], p2);
            }
            p0 += __shfl_xor(p0, 16, 64); p0 += __shfl_xor(p0, 32, 64);
            p1 += __shfl_xor(p1, 16, 64); p1 += __shfl_xor(p1, 32, 64);
            p2 += __shfl_xor(p2, 16, 64); p2 += __shfl_xor(p2, 32, 64);
            // quad c (0..2) stores channel c of point (t0+s)*16+row
            float y  = (quad == 0) ? p0 : ((quad == 1) ? p1 : p2);
            float e  = __builtin_amdgcn_exp2f(y);
            float sg = __builtin_amdgcn_rcpf(e + 1.0f);
            if (quad < 3) {
                out[((t0 + s) * 16 + row) * 3 + quad] = sg;
            }
        }
    }
}

extern "C" void kernel_launch(void* const* d_in, const int* in_sizes, int n_in,
                              void* d_out, int out_size, void* d_ws, size_t ws_size,
                              hipStream_t stream) {
    const float2* x    = (const float2*)d_in[0];
    const float2* Win  = (const float2*)d_in[1];
    const float*  bin  = (const float*) d_in[2];
    const float4* Wh   = (const float4*)d_in[3];
    const float4* Wout = (const float4*)d_in[4];
    float* out = (float*)d_out;

    const int n      = in_sizes[0] / 2;   // 4,194,304 points
    const int nPairs = n / 32;            // 2 tiles of 16 points per wave-iter
    const int blocks = 1024;              // 4096 waves, 4/SIMD resident
    const int nWaves = blocks * 4;

    artnet_kernel<<<blocks, 256, 0, stream>>>(x, Win, bin, Wh, Wout, out, nPairs, nWaves);
}